// Round 12
// baseline (172.230 us; speedup 1.0000x reference)
//
#include <hip/hip_runtime.h>
#include <hip/hip_cooperative_groups.h>

namespace cg = cooperative_groups;

// Problem constants (from reference): B=128, D_IN=64, N=50000, NNZ=800000
#define B_    128
#define DIN_  64
#define NN_   50000
#define NNZ_  800000
#define CAP_  64      // slots per column. deg ~ Poisson(16); P(deg>=64) ~ 1e-19.

#define GEMM_TILES_   782    // ceil(50000/64)
#define GATHER_TILES_ 1563   // ceil(50000/32)

// round-to-nearest-even f32 -> bf16 bits
__device__ __forceinline__ unsigned short f2bf(float f) {
    unsigned int u = __float_as_uint(f);
    u += 0x7FFFu + ((u >> 16) & 1u);
    return (unsigned short)(u >> 16);
}

// ---------------------------------------------------------------------------
// ONE cooperative kernel, 3 phases (round-9 evidence: ~15us per graph node
// transition x 3 nodes ~= 45us of the 165us total was dispatch overhead).
// Phase 0: zero cnt.                  grid.sync
// Phase 1: even blocks gemm (coalesced-W, LDS-x), odd blocks bucket
//          (complementary profiles overlap per-CU).   grid.sync
// Phase 2: gather 32 cols/tile + in-LDS transpose -> out[B][N].
// LDS: 64x132 f32 (33792B) for xs_t, reused as 128x33 tile in phase 2.
// 4 blocks/CU co-resident -> grid = 4*256 = 1024 (occupancy-derived).
// ---------------------------------------------------------------------------
__global__ __launch_bounds__(512) void fused_all(const float* __restrict__ x,
                                                 const float* __restrict__ W,
                                                 unsigned short* __restrict__ m_bf,
                                                 const int* __restrict__ rows,
                                                 const int* __restrict__ cols,
                                                 const float* __restrict__ vals,
                                                 int* __restrict__ cnt,
                                                 unsigned int* __restrict__ csc,
                                                 float* __restrict__ out) {
    __shared__ float smem[DIN_ * 132];   // 33792 B
    cg::grid_group grid = cg::this_grid();
    const int t   = threadIdx.x;
    const int blk = blockIdx.x;
    const int nb  = gridDim.x;

    // ---- phase 0: zero cnt ----
    for (int i = blk * 512 + t; i < NN_; i += nb * 512)
        cnt[i] = 0;
    grid.sync();

    // ---- phase 1: role split ----
    if (blk & 1) {
        // bucket role: odd blocks, grid-stride over edges
        const int nbb = nb >> 1;
        const int idx = blk >> 1;
        for (int e = idx * 512 + t; e < NNZ_; e += nbb * 512) {
            const int c = cols[e];
            const int pos = atomicAdd(&cnt[c], 1);
            if (pos < CAP_)
                csc[((unsigned int)c << 6) + pos] =
                    ((unsigned int)rows[e] << 16) | (unsigned int)f2bf(vals[e]);
        }
    } else {
        // gemm role: even blocks, grid-stride over 64-column tiles
        float (*xs_t)[132] = reinterpret_cast<float (*)[132]>(smem);
        for (int i = t; i < B_ * DIN_; i += 512)
            xs_t[i & 63][i >> 6] = x[i];
        __syncthreads();

        const int nbg = (nb + 1) >> 1;
        const int idx = blk >> 1;
        const int l   = t & 63;
        const int b0  = (t >> 6) * 16;

        for (int tile = idx; tile < GEMM_TILES_; tile += nbg) {
            const int n  = tile * 64 + l;
            const int nc = n < NN_ ? n : NN_ - 1;   // clamped loads; store guarded

            float acc[16];
            #pragma unroll
            for (int j = 0; j < 16; ++j) acc[j] = 0.f;

            const float* Wp = W + nc;
            float wcur[8], wnxt[8];
            #pragma unroll
            for (int q = 0; q < 8; ++q) wcur[q] = Wp[(size_t)q * NN_];

            for (int k = 0; k < DIN_; k += 8) {
                const int kn = k + 8;
                if (kn < DIN_) {
                    #pragma unroll
                    for (int q = 0; q < 8; ++q) wnxt[q] = Wp[(size_t)(kn + q) * NN_];
                }
                #pragma unroll
                for (int q = 0; q < 8; ++q) {
                    const float wv = wcur[q];
                    const float4* xp = reinterpret_cast<const float4*>(&xs_t[k + q][b0]);
                    const float4 x0 = xp[0], x1 = xp[1], x2 = xp[2], x3 = xp[3];
                    acc[0]  += wv * x0.x;  acc[1]  += wv * x0.y;
                    acc[2]  += wv * x0.z;  acc[3]  += wv * x0.w;
                    acc[4]  += wv * x1.x;  acc[5]  += wv * x1.y;
                    acc[6]  += wv * x1.z;  acc[7]  += wv * x1.w;
                    acc[8]  += wv * x2.x;  acc[9]  += wv * x2.y;
                    acc[10] += wv * x2.z;  acc[11] += wv * x2.w;
                    acc[12] += wv * x3.x;  acc[13] += wv * x3.y;
                    acc[14] += wv * x3.z;  acc[15] += wv * x3.w;
                }
                #pragma unroll
                for (int q = 0; q < 8; ++q) wcur[q] = wnxt[q];
            }

            if (n < NN_) {
                unsigned int pk[8];
                #pragma unroll
                for (int j = 0; j < 8; ++j)
                    pk[j] = (unsigned int)f2bf(acc[2 * j]) |
                            ((unsigned int)f2bf(acc[2 * j + 1]) << 16);
                uint4* op = reinterpret_cast<uint4*>(m_bf + (size_t)n * B_ + b0);
                op[0] = make_uint4(pk[0], pk[1], pk[2], pk[3]);
                op[1] = make_uint4(pk[4], pk[5], pk[6], pk[7]);
            }
        }
    }
    grid.sync();

    // ---- phase 2: gather + in-LDS transpose, 32 cols per tile ----
    float (*tile)[33] = reinterpret_cast<float (*)[33]>(smem);
    const int g2   = t >> 6;
    const int lane = t & 63;

    for (int tt = blk; tt < GATHER_TILES_; tt += nb) {
        const int c0 = tt * 32;

        #pragma unroll
        for (int cl = 0; cl < 4; ++cl) {
            const int c = c0 + g2 * 4 + cl;
            float acc0 = 0.f, acc1 = 0.f;
            if (c < NN_) {
                const unsigned int* ce = &csc[(unsigned int)c << 6];
                int n = cnt[c]; if (n > CAP_) n = CAP_;
                int e = 0;
                for (; e + 7 < n; e += 8) {
                    unsigned int p[8], mm[8];
                    #pragma unroll
                    for (int q = 0; q < 8; ++q) p[q] = ce[e + q];
                    #pragma unroll
                    for (int q = 0; q < 8; ++q)
                        mm[q] = *(const unsigned int*)(m_bf + (((size_t)(p[q] >> 16)) << 7) + (lane << 1));
                    #pragma unroll
                    for (int q = 0; q < 8; ++q) {
                        const float v = __uint_as_float(p[q] << 16);
                        acc0 += __uint_as_float(mm[q] << 16)         * v;
                        acc1 += __uint_as_float(mm[q] & 0xFFFF0000u) * v;
                    }
                }
                for (; e < n; ++e) {
                    const unsigned int p = ce[e];
                    const unsigned int m = *(const unsigned int*)(m_bf + (((size_t)(p >> 16)) << 7) + (lane << 1));
                    const float v = __uint_as_float(p << 16);
                    acc0 += __uint_as_float(m << 16)         * v;
                    acc1 += __uint_as_float(m & 0xFFFF0000u) * v;
                }
            }
            tile[2 * lane][g2 * 4 + cl]     = acc0;
            tile[2 * lane + 1][g2 * 4 + cl] = acc1;
        }
        __syncthreads();

        // write-out: thread t -> row r = t>>2, segment seg = t&3 (8 cols)
        const int r = t >> 2, seg = t & 3;
        const int cbase = c0 + seg * 8;
        const float* tr = &tile[r][seg * 8];
        if (cbase + 7 < NN_) {
            float4* op = reinterpret_cast<float4*>(&out[(size_t)r * NN_ + cbase]);
            op[0] = make_float4(tr[0], tr[1], tr[2], tr[3]);
            op[1] = make_float4(tr[4], tr[5], tr[6], tr[7]);
        } else {
            for (int j = 0; j < 8; ++j)
                if (cbase + j < NN_) out[(size_t)r * NN_ + cbase + j] = tr[j];
        }
        __syncthreads();   // before next iteration overwrites tile
    }
}

// ===========================================================================
// Fallback path (round-9 3-kernel pipeline), used if cooperative launch is
// unavailable. Identical math.
// ===========================================================================
#define BUCKET_BLOCKS_ 1563
#define FUSED_BLOCKS_  2345

__global__ __launch_bounds__(512) void fused_gb(const float* __restrict__ x,
                                                const float* __restrict__ W,
                                                unsigned short* __restrict__ m_bf,
                                                const int* __restrict__ rows,
                                                const int* __restrict__ cols,
                                                const float* __restrict__ vals,
                                                int* __restrict__ cnt,
                                                unsigned int* __restrict__ csc) {
    __shared__ float xs_t[DIN_][132];
    const int t = threadIdx.x;
    const int g = blockIdx.x / 3;
    const int r = blockIdx.x % 3;

    if (r != 0) {
        const int bid = 2 * g + (r - 1);
        if (bid >= BUCKET_BLOCKS_) return;
        const int e = bid * 512 + t;
        if (e >= NNZ_) return;
        const int c = cols[e];
        const int pos = atomicAdd(&cnt[c], 1);
        if (pos < CAP_)
            csc[((unsigned int)c << 6) + pos] =
                ((unsigned int)rows[e] << 16) | (unsigned int)f2bf(vals[e]);
        return;
    }

    for (int i = t; i < B_ * DIN_; i += 512)
        xs_t[i & 63][i >> 6] = x[i];
    __syncthreads();

    const int l  = t & 63;
    const int n  = g * 64 + l;
    const int nc = n < NN_ ? n : NN_ - 1;
    const int b0 = (t >> 6) * 16;

    float acc[16];
    #pragma unroll
    for (int j = 0; j < 16; ++j) acc[j] = 0.f;

    const float* Wp = W + nc;
    float wcur[8], wnxt[8];
    #pragma unroll
    for (int q = 0; q < 8; ++q) wcur[q] = Wp[(size_t)q * NN_];

    for (int k = 0; k < DIN_; k += 8) {
        const int kn = k + 8;
        if (kn < DIN_) {
            #pragma unroll
            for (int q = 0; q < 8; ++q) wnxt[q] = Wp[(size_t)(kn + q) * NN_];
        }
        #pragma unroll
        for (int q = 0; q < 8; ++q) {
            const float wv = wcur[q];
            const float4* xp = reinterpret_cast<const float4*>(&xs_t[k + q][b0]);
            const float4 x0 = xp[0], x1 = xp[1], x2 = xp[2], x3 = xp[3];
            acc[0]  += wv * x0.x;  acc[1]  += wv * x0.y;
            acc[2]  += wv * x0.z;  acc[3]  += wv * x0.w;
            acc[4]  += wv * x1.x;  acc[5]  += wv * x1.y;
            acc[6]  += wv * x1.z;  acc[7]  += wv * x1.w;
            acc[8]  += wv * x2.x;  acc[9]  += wv * x2.y;
            acc[10] += wv * x2.z;  acc[11] += wv * x2.w;
            acc[12] += wv * x3.x;  acc[13] += wv * x3.y;
            acc[14] += wv * x3.z;  acc[15] += wv * x3.w;
        }
        #pragma unroll
        for (int q = 0; q < 8; ++q) wcur[q] = wnxt[q];
    }

    if (n < NN_) {
        unsigned int pk[8];
        #pragma unroll
        for (int j = 0; j < 8; ++j)
            pk[j] = (unsigned int)f2bf(acc[2 * j]) |
                    ((unsigned int)f2bf(acc[2 * j + 1]) << 16);
        uint4* op = reinterpret_cast<uint4*>(m_bf + (size_t)n * B_ + b0);
        op[0] = make_uint4(pk[0], pk[1], pk[2], pk[3]);
        op[1] = make_uint4(pk[4], pk[5], pk[6], pk[7]);
    }
}

__global__ __launch_bounds__(256) void gather_k(const unsigned short* __restrict__ m_bf,
                                                const int* __restrict__ cnt,
                                                const unsigned int* __restrict__ csc,
                                                float* __restrict__ out) {
    __shared__ float tile[B_][17];
    const int t    = threadIdx.x;
    const int g    = t >> 6;
    const int lane = t & 63;
    const int c0   = blockIdx.x * 16;

    #pragma unroll
    for (int cl = 0; cl < 4; ++cl) {
        const int c = c0 + g * 4 + cl;
        const unsigned int* ce = &csc[(unsigned int)c << 6];
        int n = cnt[c]; if (n > CAP_) n = CAP_;
        float acc0 = 0.f, acc1 = 0.f;
        int e = 0;
        for (; e + 7 < n; e += 8) {
            unsigned int p[8], mm[8];
            #pragma unroll
            for (int q = 0; q < 8; ++q) p[q] = ce[e + q];
            #pragma unroll
            for (int q = 0; q < 8; ++q)
                mm[q] = *(const unsigned int*)(m_bf + (((size_t)(p[q] >> 16)) << 7) + (lane << 1));
            #pragma unroll
            for (int q = 0; q < 8; ++q) {
                const float v = __uint_as_float(p[q] << 16);
                acc0 += __uint_as_float(mm[q] << 16)         * v;
                acc1 += __uint_as_float(mm[q] & 0xFFFF0000u) * v;
            }
        }
        for (; e < n; ++e) {
            const unsigned int p = ce[e];
            const unsigned int m = *(const unsigned int*)(m_bf + (((size_t)(p >> 16)) << 7) + (lane << 1));
            const float v = __uint_as_float(p << 16);
            acc0 += __uint_as_float(m << 16)         * v;
            acc1 += __uint_as_float(m & 0xFFFF0000u) * v;
        }
        tile[2 * lane][g * 4 + cl]     = acc0;
        tile[2 * lane + 1][g * 4 + cl] = acc1;
    }
    __syncthreads();

    const int r = t >> 1, h = t & 1;
    const float* tr = &tile[r][h * 8];
    float4* op = reinterpret_cast<float4*>(&out[(size_t)r * NN_ + c0 + h * 8]);
    op[0] = make_float4(tr[0], tr[1], tr[2], tr[3]);
    op[1] = make_float4(tr[4], tr[5], tr[6], tr[7]);
}

__global__ __launch_bounds__(256) void scatter_onfly(const float* __restrict__ x,
                                                     const float* __restrict__ W,
                                                     const int* __restrict__ rows,
                                                     const int* __restrict__ cols,
                                                     const float* __restrict__ vals,
                                                     float* __restrict__ out) {
    const unsigned int gid = blockIdx.x * 256u + threadIdx.x;
    const unsigned int e = gid >> 7;
    const unsigned int b = gid & 127u;
    if (e >= NNZ_) return;
    const int   r = rows[e];
    const int   c = cols[e];
    const float v = vals[e];
    float dot = 0.f;
    for (int k = 0; k < DIN_; ++k)
        dot += x[b * DIN_ + k] * W[(size_t)k * NN_ + r];
    atomicAdd(&out[(size_t)b * NN_ + c], dot * v);
}

extern "C" void kernel_launch(void* const* d_in, const int* in_sizes, int n_in,
                              void* d_out, int out_size, void* d_ws, size_t ws_size,
                              hipStream_t stream) {
    const float* x    = (const float*)d_in[0];
    const float* W    = (const float*)d_in[1];
    const int*   rows = (const int*)d_in[2];
    const int*   cols = (const int*)d_in[3];
    const float* vals = (const float*)d_in[4];
    float* out = (float*)d_out;

    const size_t mbf_bytes = (size_t)NN_ * B_ * sizeof(unsigned short); // 12,800,000
    const size_t cnt_bytes = (size_t)NN_ * sizeof(int);                 //    200,000
    const size_t csc_bytes = (size_t)NN_ * CAP_ * sizeof(unsigned int); // 12,800,000
    const size_t need = mbf_bytes + cnt_bytes + csc_bytes;              // ~25.8 MB

    if (ws_size >= need) {
        char* p = (char*)d_ws;
        unsigned short* m_bf = (unsigned short*)p;  p += mbf_bytes;
        int*            cnt  = (int*)p;             p += cnt_bytes;
        unsigned int*   csc  = (unsigned int*)p;

        // Cooperative single-kernel path: grid = co-resident capacity.
        int maxb = 0;
        hipError_t oerr = hipOccupancyMaxActiveBlocksPerMultiprocessor(
            &maxb, (const void*)fused_all, 512, 0);
        bool done = false;
        if (oerr == hipSuccess && maxb > 0) {
            int grid = maxb * 256;
            if (grid > GATHER_TILES_) grid = GATHER_TILES_;  // no need for more
            void* args[] = {(void*)&x, (void*)&W, (void*)&m_bf, (void*)&rows,
                            (void*)&cols, (void*)&vals, (void*)&cnt, (void*)&csc,
                            (void*)&out};
            hipError_t lerr = hipLaunchCooperativeKernel(
                (const void*)fused_all, dim3(grid), dim3(512), args, 0, stream);
            done = (lerr == hipSuccess);
        }
        if (!done) {
            // Fallback: round-9 3-kernel pipeline.
            hipMemsetAsync(cnt, 0, cnt_bytes, stream);
            fused_gb<<<FUSED_BLOCKS_, 512, 0, stream>>>(x, W, m_bf, rows, cols, vals, cnt, csc);
            gather_k<<<NN_ / 16, 256, 0, stream>>>(m_bf, cnt, csc, out);
        }
    } else {
        // Fallback: no scratch — recompute m per edge, atomics into out.
        const int scatter_blocks = (NNZ_ * 128) / 256;
        hipMemsetAsync(out, 0, (size_t)NN_ * B_ * sizeof(float), stream);
        scatter_onfly<<<scatter_blocks, 256, 0, stream>>>(x, W, rows, cols, vals, out);
    }
}